// Round 14
// baseline (141.570 us; speedup 1.0000x reference)
//
#include <hip/hip_runtime.h>

// B=32, S=127, new_seq=128, D=768, H=12, HD=64
#define NB 32
#define NS 128
#define SD 127
#define ND 768
#define NH 12
#define HD 64

__device__ inline float wredSum(float v){
  #pragma unroll
  for (int off=32; off>0; off>>=1) v += __shfl_xor(v, off);
  return v;
}
__device__ inline float wredMax(float v){
  #pragma unroll
  for (int off=32; off>0; off>>=1) v = fmaxf(v, __shfl_xor(v, off));
  return v;
}
__device__ inline unsigned short f2bf(float x){          // RNE f32->bf16
  unsigned u = __float_as_uint(x);
  u += 0x7fffu + ((u>>16)&1u);
  return (unsigned short)(u>>16);
}
__device__ inline float bflo(unsigned v){ return __uint_as_float(v<<16); }
__device__ inline float bfhi(unsigned v){ return __uint_as_float(v & 0xffff0000u); }

// N0: fold uk (144 blocks) + bkdot (blk 0). Tiny: 2.25 MB read.
__global__ __launch_bounds__(256)
void fold_k(const float* __restrict__ Wk, const float* __restrict__ bk,
            const float* __restrict__ Wa, float* __restrict__ uk,
            float* __restrict__ bkdot){
  int blk = blockIdx.x, t = threadIdx.x;
  __shared__ float red[4][64];
  int h = blk/12, cb = blk%12;
  int c0 = t & 63, dg = t >> 6;
  const float* base = Wk + (size_t)(h*HD + dg*16)*ND + cb*64 + c0;
  float acc = 0.f;
  #pragma unroll
  for (int i=0;i<16;++i) acc += base[(size_t)i*ND] * Wa[64 + dg*16 + i];
  red[dg][c0] = acc;
  __syncthreads();
  if (dg==0) uk[h*ND + cb*64 + c0] = red[0][c0]+red[1][c0]+red[2][c0]+red[3][c0];
  if (blk==0 && t < NH){
    float a = 0.f;
    for (int d=0; d<64; ++d) a += bk[t*HD+d]*Wa[64+d];
    bkdot[t] = a;
  }
}

// N1: blocks [0,1024) lk rows (4 rows/block, uk in regs); [1024,5088) ei rows.
// lk and ei are independent -> run concurrently in one node.
__global__ __launch_bounds__(256)
void lk_ei(const float* __restrict__ nv, const float* __restrict__ desc,
           const float* __restrict__ uk, const float* __restrict__ bkdot,
           const float* __restrict__ Wa,
           float* __restrict__ lk, float* __restrict__ ei){
  __shared__ __align__(16) float S[4*ND];
  int blk = blockIdx.x, t = threadIdx.x, wave = t>>6, lane = t&63;
  if (blk < 1024){
    float ukr[3][12], bkd[3];
    #pragma unroll
    for (int hh=0; hh<3; ++hh){
      int h = wave*3 + hh;
      bkd[hh] = bkdot[h];
      #pragma unroll
      for (int k=0;k<12;++k) ukr[hh][k] = uk[h*ND + lane + 64*k];
    }
    int j0 = blk*4;                        // 4 rows, same b (128 | 4)
    const float4* src = (const float4*)(nv + (size_t)j0*ND);
    ((float4*)S)[t]     = src[t];
    ((float4*)S)[t+256] = src[t+256];
    ((float4*)S)[t+512] = src[t+512];
    __syncthreads();
    float acc[12];
    #pragma unroll
    for (int rr=0; rr<4; ++rr)
      #pragma unroll
      for (int hh=0; hh<3; ++hh){
        float a = 0.f;
        #pragma unroll
        for (int k=0;k<12;++k) a += S[rr*ND + lane + 64*k]*ukr[hh][k];
        acc[rr*3+hh] = a;
      }
    #pragma unroll
    for (int i=0;i<12;++i) acc[i] = wredSum(acc[i]);
    if (lane == 0){
      int b = j0 >> 7, jb = j0 & 127;
      #pragma unroll
      for (int rr=0; rr<4; ++rr)
        #pragma unroll
        for (int hh=0; hh<3; ++hh)
          lk[(size_t)(b*NH + wave*3 + hh)*NS + jb + rr] = acc[rr*3+hh] + bkd[hh];
    }
  } else {
    int bs = blk - 1024;                 // 0..4063
    int b = bs / SD, s = bs % SD;
    float wea = Wa[128 + lane];
    const float* row = desc + (size_t)bs * ND;
    #pragma unroll
    for (int hh=0; hh<3; ++hh){
      int h = wave + hh*4;
      float v = row[h*HD + lane] * wea;
      v = wredSum(v);
      if (lane==0) ei[(size_t)(b*NH + h)*NS + s] = v;
    }
  }
}

// N2: per (b,jg16): all-24 softmax -> m partials over 8 j's (waves 0-2, bf16
// output) + attn-tile rows [jg*8,jg*8+8). 512 blocks = 2/CU.
__global__ __launch_bounds__(256)
void msoft_attn(const float* __restrict__ nv, const float* __restrict__ lk,
                const float* __restrict__ ei, unsigned short* __restrict__ m_part,
                float* __restrict__ out){
  int blk = blockIdx.x;               // b*16 + jg
  int b = blk >> 4, jg = blk & 15;
  int t = threadIdx.x, wave = t >> 6, lane = t & 63;
  __shared__ float slk[NH*NS];
  __shared__ float sei[NH*NS];
  __shared__ float wf[24][NS];
  for (int i=t; i<NH*NS; i+=256) slk[i] = lk[(size_t)b*NH*NS + i];
  for (int i=t; i<NH*NS; i+=256) sei[i] = ei[(size_t)b*NH*NS + i];
  __syncthreads();
  #pragma unroll
  for (int rr=0; rr<6; ++rr){
    int r = wave*6 + rr;
    int h = r >> 1, which = r & 1;
    const float* eirow = (which==0) ? (sei + (h%6)*NS) : (sei + h*NS);
    float g = (which==0) ? 1.f : (h>=6 ? 1.f : 0.f);
    float x0 = (lane>=1) ? slk[h*NS+lane] + g*eirow[lane-1] : -3.0e38f;
    float x1 = slk[h*NS+lane+64] + g*eirow[lane+63];
    float mm = wredMax(fmaxf(x0,x1));
    float e0 = (lane>=1) ? __expf(x0-mm) : 0.f;  // col 0 masked -> exactly 0
    float e1 = __expf(x1-mm);
    float s  = wredSum(e0+e1);
    float inv = 1.f/s;
    wf[r][lane]    = e0*inv;
    wf[r][lane+64] = e1*inv;
  }
  __syncthreads();
  if (t < 192){                        // waves 0-2: m partials over 8 j's
    const float4* nvb = (const float4*)(nv + ((size_t)b*NS + jg*8)*ND);
    float4 acc[24];
    #pragma unroll
    for (int r=0;r<24;++r) acc[r] = make_float4(0.f,0.f,0.f,0.f);
    #pragma unroll
    for (int jj=0; jj<8; ++jj){
      float4 x = nvb[jj*192 + t];
      int j = jg*8 + jj;
      #pragma unroll
      for (int r=0;r<24;++r){
        float wr = wf[r][j];           // LDS broadcast, conflict-free
        acc[r].x += wr*x.x; acc[r].y += wr*x.y;
        acc[r].z += wr*x.z; acc[r].w += wr*x.w;
      }
    }
    #pragma unroll
    for (int r=0;r<24;++r){
      ushort4 pk = { f2bf(acc[r].x), f2bf(acc[r].y), f2bf(acc[r].z), f2bf(acc[r].w) };
      ((ushort4*)(m_part + ((size_t)(b*24 + r)*16 + jg)*ND))[t] = pk;
    }
  }
  // attn rows [jg*8, jg*8+8) for all 12 heads: 3072 float4
  float* abase = out + (size_t)NB*NS*ND + (size_t)(b*NH)*NS*NS;
  for (int idx=t; idx<3072; idx+=256){
    int h = idx >> 8;
    int rem = idx & 255;
    int il = rem >> 5, q = rem & 31;
    int i = jg*8 + il;
    const float* srcw = (i==0) ? wf[h*2] : wf[h*2+1];
    float4 v = { srcw[q*4], srcw[q*4+1], srcw[q*4+2], srcw[q*4+3] };
    ((float4*)(abase + (size_t)h*NS*NS))[i*32 + q] = v;
  }
}

// N3: per (b,h): sum 16 bf16 partials -> V-proj -> basis write
__global__ __launch_bounds__(256)
void proj_basis(const unsigned short* __restrict__ m_part,
                const float* __restrict__ Wv, const float* __restrict__ bv,
                float* __restrict__ out){
  int bh = blockIdx.x;                // 0..383
  int b = bh / NH, h = bh % NH;
  int t = threadIdx.x, wave = t >> 6, lane = t & 63;
  __shared__ __align__(16) float msum[2*ND];
  __shared__ float cvec[2*HD];
  if (t < 192){                       // 192 = 2 rows x 96 uint4 (8 bf16 each)
    int rl = t / 96, c8 = t % 96;
    const uint4* mp = (const uint4*)(m_part + ((size_t)(b*24 + h*2 + rl)*16)*ND) + c8;
    float s[8] = {0.f,0.f,0.f,0.f,0.f,0.f,0.f,0.f};
    #pragma unroll
    for (int g=0; g<16; ++g){
      uint4 v = mp[g*96];
      s[0]+=bflo(v.x); s[1]+=bfhi(v.x); s[2]+=bflo(v.y); s[3]+=bfhi(v.y);
      s[4]+=bflo(v.z); s[5]+=bfhi(v.z); s[6]+=bflo(v.w); s[7]+=bfhi(v.w);
    }
    #pragma unroll
    for (int k=0;k<8;++k) msum[rl*ND + c8*8 + k] = s[k];
  }
  __syncthreads();
  #pragma unroll
  for (int dd=0; dd<16; ++dd){
    int d = wave*16 + dd;
    const float* wvr = Wv + (size_t)(h*HD + d)*ND;
    float p0=0.f, p1=0.f;
    #pragma unroll
    for (int k=0; k<12; ++k){
      float wv = wvr[lane + 64*k];
      p0 += wv*msum[lane + 64*k];
      p1 += wv*msum[ND + lane + 64*k];
    }
    p0 = wredSum(p0); p1 = wredSum(p1);
    if (lane==0){
      float bb = bv[h*HD + d];
      cvec[d]    = p0 + bb;
      cvec[64+d] = p1 + bb;
    }
  }
  __syncthreads();
  float* bo = out + (size_t)b*NS*ND + h*HD;
  #pragma unroll
  for (int k=0;k<8;++k){
    int idx = t + k*256;              // 2048 float4
    int i = idx>>4, q = idx&15;
    const float* srcc = (i==0) ? cvec : cvec+64;
    float4 v = { srcc[q*4], srcc[q*4+1], srcc[q*4+2], srcc[q*4+3] };
    *(float4*)(bo + (size_t)i*ND + q*4) = v;
  }
}

extern "C" void kernel_launch(void* const* d_in, const int* in_sizes, int n_in,
                              void* d_out, int out_size, void* d_ws, size_t ws_size,
                              hipStream_t stream) {
  const float* desc = (const float*)d_in[0];
  const float* nv   = (const float*)d_in[1];
  // d_in[2]=Wq, d_in[3]=bq: unused (softmax shift-invariance)
  const float* Wk   = (const float*)d_in[4];
  const float* bk   = (const float*)d_in[5];
  const float* Wv   = (const float*)d_in[6];
  const float* bv   = (const float*)d_in[7];
  const float* Wa   = (const float*)d_in[8];
  // d_in[9]=ba: unused (constant shift)
  float* out = (float*)d_out;
  float* ws  = (float*)d_ws;

  float* uk     = ws;               // 9216
  float* bkdot  = ws + 9216;        // 16
  float* eibuf  = ws + 9232;        // 49152
  float* lkbuf  = ws + 58384;       // 49152
  unsigned short* m_part = (unsigned short*)(ws + 107536); // 32*24*16*768 bf16 = 18.9 MB

  fold_k    <<<144,  256, 0, stream>>>(Wk, bk, Wa, uk, bkdot);
  lk_ei     <<<5088, 256, 0, stream>>>(nv, desc, uk, bkdot, Wa, lkbuf, eibuf);
  msoft_attn<<<512,  256, 0, stream>>>(nv, lkbuf, eibuf, m_part, out);
  proj_basis<<<384,  256, 0, stream>>>(m_part, Wv, bv, out);
}